// Round 5
// baseline (489.287 us; speedup 1.0000x reference)
//
#include <hip/hip_runtime.h>
#include <hip/hip_bf16.h>

#define NQ 8192
#define NG 2048
#define CTX 64
#define DQ 512
#define DK 256
#define DV 256
#define DZ 256

typedef __attribute__((ext_vector_type(8))) short short8;
typedef __attribute__((ext_vector_type(4))) float f32x4;

__device__ __forceinline__ unsigned short f2bf_bits(float f) {
  __hip_bfloat16 h = __float2bfloat16(f);
  return __builtin_bit_cast(unsigned short, h);
}
__device__ __forceinline__ float bf2f(unsigned short u) {
  unsigned int x = ((unsigned int)u) << 16;
  return __builtin_bit_cast(float, x);
}
__device__ __forceinline__ void split2(float x, unsigned short& h, unsigned short& l) {
  h = f2bf_bits(x);
  l = f2bf_bits(x - bf2f(h));
}
__device__ __forceinline__ void cvt8_hl(f32x4 f0, f32x4 f1, short8& h8, short8& l8) {
#pragma unroll
  for (int j = 0; j < 4; j++) { unsigned short h, l; split2(f0[j], h, l); h8[j] = (short)h; l8[j] = (short)l; }
#pragma unroll
  for (int j = 0; j < 4; j++) { unsigned short h, l; split2(f1[j], h, l); h8[4 + j] = (short)h; l8[4 + j] = (short)l; }
}
__device__ __forceinline__ short8 cvt8_h(f32x4 f0, f32x4 f1) {
  short8 h8;
#pragma unroll
  for (int j = 0; j < 4; j++) h8[j] = (short)f2bf_bits(f0[j]);
#pragma unroll
  for (int j = 0; j < 4; j++) h8[4 + j] = (short)f2bf_bits(f1[j]);
  return h8;
}

// ---------------- prep: split+transpose weights, group ranges, flag init ----------------
__global__ void prep_kernel(const float* __restrict__ Wq, const float* __restrict__ Wk,
                            const int* __restrict__ gidx,
                            unsigned short* __restrict__ WqTh, unsigned short* __restrict__ WqTl,
                            unsigned short* __restrict__ WkTh, unsigned short* __restrict__ WkTl,
                            int* __restrict__ starts, int* __restrict__ mflag)
{
  int t = blockIdx.x * 256 + threadIdx.x;
  if (t < DZ * DQ) {                       // WqT*[z][kq] = Wq[kq][z]
    int z = t >> 9, kq = t & 511;
    unsigned short h, l; split2(Wq[(size_t)kq * DZ + z], h, l);
    WqTh[t] = h; WqTl[t] = l;
  } else if (t < DZ * DQ + DZ * DK) {      // WkT*[z][kx] = Wk[kx][z]
    int u = t - DZ * DQ;
    int z = u >> 8, kx = u & 255;
    unsigned short h, l; split2(Wk[(size_t)kx * DZ + z], h, l);
    WkTh[u] = h; WkTl[u] = l;
  } else if (t < DZ * DQ + DZ * DK + NG + 1) {
    int g = t - (DZ * DQ + DZ * DK);
    int lo = 0, hi = NQ;
    while (lo < hi) { int mid = (lo + hi) >> 1; if (gidx[mid] < g) lo = mid + 1; else hi = mid; }
    starts[g] = lo;
  } else if (t == DZ * DQ + DZ * DK + NG + 1) {
    mflag[0] = 0;
  }
}

// ---------------- mask dtype scan: flag=1 iff mask is 1-byte elements ----------------
__global__ void maskscan_kernel(const unsigned int* __restrict__ mw, int* __restrict__ flag)
{
  int i = blockIdx.x * 256 + threadIdx.x;
  unsigned int w = mw[i];
  bool bad = (w != 0u && w != 1u && w != 0x3F800000u);
  if (__any(bad) && ((threadIdx.x & 63) == 0))
    atomicOr(flag, 1);
}

// ---------------- qz = (q @ Wq + bq) * 1/16, stored as split bf16 pair ----------------
__global__ __launch_bounds__(256, 4) void qz_kernel(
    const float* __restrict__ q, const float* __restrict__ bq,
    const unsigned short* __restrict__ WqTh, const unsigned short* __restrict__ WqTl,
    unsigned short* __restrict__ qzh, unsigned short* __restrict__ qzl)
{
  const int tid = threadIdx.x;
  const int wave = tid >> 6, lane = tid & 63;
  const int i16 = lane & 15, hi4 = lane >> 4;
  const int mbase = blockIdx.x * 32;

  f32x4 acc[2][4];
#pragma unroll
  for (int a = 0; a < 2; a++)
#pragma unroll
    for (int b = 0; b < 4; b++) acc[a][b] = {0.f, 0.f, 0.f, 0.f};

  for (int kk = 0; kk < DQ; kk += 32) {
    f32x4 araw[2][2];
#pragma unroll
    for (int mt = 0; mt < 2; mt++) {
      const float* src = q + (size_t)(mbase + mt * 16 + i16) * DQ + kk + hi4 * 8;
      araw[mt][0] = *reinterpret_cast<const f32x4*>(src);
      araw[mt][1] = *reinterpret_cast<const f32x4*>(src + 4);
    }
    short8 ah[2], al[2];
#pragma unroll
    for (int mt = 0; mt < 2; mt++) cvt8_hl(araw[mt][0], araw[mt][1], ah[mt], al[mt]);

#pragma unroll
    for (int ntp = 0; ntp < 2; ntp++) {
      short8 bh[2], bl[2];
#pragma unroll
      for (int j = 0; j < 2; j++) {
        const int n = wave * 64 + (ntp * 2 + j) * 16 + i16;
        bh[j] = *reinterpret_cast<const short8*>(WqTh + (size_t)n * DQ + kk + hi4 * 8);
        bl[j] = *reinterpret_cast<const short8*>(WqTl + (size_t)n * DQ + kk + hi4 * 8);
      }
#pragma unroll
      for (int mt = 0; mt < 2; mt++)
#pragma unroll
        for (int j = 0; j < 2; j++) {
          f32x4 a = acc[mt][ntp * 2 + j];
          a = __builtin_amdgcn_mfma_f32_16x16x32_bf16(ah[mt], bh[j], a, 0, 0, 0);
          a = __builtin_amdgcn_mfma_f32_16x16x32_bf16(al[mt], bh[j], a, 0, 0, 0);
          a = __builtin_amdgcn_mfma_f32_16x16x32_bf16(ah[mt], bl[j], a, 0, 0, 0);
          acc[mt][ntp * 2 + j] = a;
        }
    }
  }

  const float scale = 0.0625f;
#pragma unroll
  for (int nt = 0; nt < 4; nt++) {
    const int n = wave * 64 + nt * 16 + i16;
    const float bias = bq[n];
#pragma unroll
    for (int mt = 0; mt < 2; mt++)
#pragma unroll
      for (int r = 0; r < 4; r++) {
        const int m = mbase + mt * 16 + hi4 * 4 + r;
        float x = (acc[mt][nt][r] + bias) * scale;
        unsigned short h, l; split2(x, h, l);
        qzh[(size_t)m * DZ + n] = h;
        qzl[(size_t)m * DZ + n] = l;
      }
  }
}

// ---------------- kz v1: R4 structure, bounds 6 (occupancy probe), rows [0,65536) ----------------
__global__ __launch_bounds__(256, 6) void kz_kernel(
    const float* __restrict__ kmat, const float* __restrict__ bk,
    const unsigned short* __restrict__ WkTh, const unsigned short* __restrict__ WkTl,
    unsigned short* __restrict__ kz)
{
  const int tid = threadIdx.x;
  const int wave = tid >> 6, lane = tid & 63;
  const int i16 = lane & 15, hi4 = lane >> 4;
  const int mbase = blockIdx.x * 64;

  f32x4 acc[4][4];
#pragma unroll
  for (int a = 0; a < 4; a++)
#pragma unroll
    for (int b = 0; b < 4; b++) acc[a][b] = {0.f, 0.f, 0.f, 0.f};

  for (int kk = 0; kk < DK; kk += 32) {
    f32x4 araw[4][2];
#pragma unroll
    for (int mt = 0; mt < 4; mt++) {
      const float* src = kmat + (size_t)(mbase + mt * 16 + i16) * DK + kk + hi4 * 8;
      araw[mt][0] = *reinterpret_cast<const f32x4*>(src);
      araw[mt][1] = *reinterpret_cast<const f32x4*>(src + 4);
    }
    short8 ah[4];
#pragma unroll
    for (int mt = 0; mt < 4; mt++) ah[mt] = cvt8_h(araw[mt][0], araw[mt][1]);

#pragma unroll
    for (int ntp = 0; ntp < 2; ntp++) {
      short8 bh[2], bl[2];
#pragma unroll
      for (int j = 0; j < 2; j++) {
        const int n = wave * 64 + (ntp * 2 + j) * 16 + i16;
        bh[j] = *reinterpret_cast<const short8*>(WkTh + (size_t)n * DK + kk + hi4 * 8);
        bl[j] = *reinterpret_cast<const short8*>(WkTl + (size_t)n * DK + kk + hi4 * 8);
      }
#pragma unroll
      for (int mt = 0; mt < 4; mt++)
#pragma unroll
        for (int j = 0; j < 2; j++) {
          f32x4 a = acc[mt][ntp * 2 + j];
          a = __builtin_amdgcn_mfma_f32_16x16x32_bf16(ah[mt], bh[j], a, 0, 0, 0);
          a = __builtin_amdgcn_mfma_f32_16x16x32_bf16(ah[mt], bl[j], a, 0, 0, 0);
          acc[mt][ntp * 2 + j] = a;
        }
    }
  }

#pragma unroll
  for (int nt = 0; nt < 4; nt++) {
    const int n = wave * 64 + nt * 16 + i16;
    const float bias = bk[n];
#pragma unroll
    for (int mt = 0; mt < 4; mt++)
#pragma unroll
      for (int r = 0; r < 4; r++) {
        const int m = mbase + mt * 16 + hi4 * 4 + r;
        kz[(size_t)m * DZ + n] = f2bf_bits(acc[mt][nt][r] + bias);
      }
  }
}

// ---------------- kz v2: pipelined (prefetch next A tile), 64x128 blocks, rows [65536,131072) ----------------
__global__ __launch_bounds__(256, 4) void kz2_kernel(
    const float* __restrict__ kmat, const float* __restrict__ bk,
    const unsigned short* __restrict__ WkTh, const unsigned short* __restrict__ WkTl,
    unsigned short* __restrict__ kz)
{
  const int tid = threadIdx.x;
  const int wave = tid >> 6, lane = tid & 63;
  const int i16 = lane & 15, hi4 = lane >> 4;
  const int mbase = 65536 + (blockIdx.x >> 1) * 64;
  const int nbase = (blockIdx.x & 1) * 128 + wave * 32;

  const float* abase = kmat + (size_t)mbase * DK;

  f32x4 acc[4][2];
#pragma unroll
  for (int a = 0; a < 4; a++)
#pragma unroll
    for (int b = 0; b < 2; b++) acc[a][b] = {0.f, 0.f, 0.f, 0.f};

  f32x4 araw[4][2];
#pragma unroll
  for (int mt = 0; mt < 4; mt++) {
    const float* src = abase + (size_t)(mt * 16 + i16) * DK + hi4 * 8;
    araw[mt][0] = *reinterpret_cast<const f32x4*>(src);
    araw[mt][1] = *reinterpret_cast<const f32x4*>(src + 4);
  }
  short8 ah[4];
#pragma unroll
  for (int mt = 0; mt < 4; mt++) ah[mt] = cvt8_h(araw[mt][0], araw[mt][1]);

#pragma unroll
  for (int it = 0; it < 8; it++) {
    const int kk = it * 32;
    if (it < 7) {   // issue next tile's loads BEFORE this tile's MFMAs
#pragma unroll
      for (int mt = 0; mt < 4; mt++) {
        const float* src = abase + (size_t)(mt * 16 + i16) * DK + (kk + 32) + hi4 * 8;
        araw[mt][0] = *reinterpret_cast<const f32x4*>(src);
        araw[mt][1] = *reinterpret_cast<const f32x4*>(src + 4);
      }
    }
    short8 bh[2], bl[2];
#pragma unroll
    for (int j = 0; j < 2; j++) {
      const int n = nbase + j * 16 + i16;
      bh[j] = *reinterpret_cast<const short8*>(WkTh + (size_t)n * DK + kk + hi4 * 8);
      bl[j] = *reinterpret_cast<const short8*>(WkTl + (size_t)n * DK + kk + hi4 * 8);
    }
#pragma unroll
    for (int mt = 0; mt < 4; mt++)
#pragma unroll
      for (int j = 0; j < 2; j++) {
        f32x4 a = acc[mt][j];
        a = __builtin_amdgcn_mfma_f32_16x16x32_bf16(ah[mt], bh[j], a, 0, 0, 0);
        a = __builtin_amdgcn_mfma_f32_16x16x32_bf16(ah[mt], bl[j], a, 0, 0, 0);
        acc[mt][j] = a;
      }
    if (it < 7) {
#pragma unroll
      for (int mt = 0; mt < 4; mt++) ah[mt] = cvt8_h(araw[mt][0], araw[mt][1]);
    }
  }

#pragma unroll
  for (int j = 0; j < 2; j++) {
    const int n = nbase + j * 16 + i16;
    const float bias = bk[n];
#pragma unroll
    for (int mt = 0; mt < 4; mt++)
#pragma unroll
      for (int r = 0; r < 4; r++) {
        const int m = mbase + mt * 16 + hi4 * 4 + r;
        kz[(size_t)m * DZ + n] = f2bf_bits(acc[mt][j][r] + bias);
      }
  }
}

// ---------------- attn v1: R4 verbatim (+gbase), groups [0,1024) ----------------
__global__ __launch_bounds__(256, 3) void attn_lite_kernel(
    const unsigned short* __restrict__ kz, const float* __restrict__ vmat,
    const void* __restrict__ mmask, const int* __restrict__ mflagp,
    const int* __restrict__ starts,
    const unsigned short* __restrict__ qzh, const unsigned short* __restrict__ qzl,
    float* __restrict__ out, int gbase)
{
  const int g = gbase + blockIdx.x;
  const int q0 = starts[g];
  const int q1 = starts[g + 1];
  if (q0 >= q1) return;

  const int tid = threadIdx.x;
  const int wave = tid >> 6, lane = tid & 63;
  const int i16 = lane & 15, hi4 = lane >> 4;

  __shared__ __align__(16) unsigned short ph_lds[CTX * 16];
  __shared__ __align__(16) unsigned short pl_lds[CTX * 16];
  __shared__ float maskbias[CTX];

  if (tid < CTX) {
    bool valid;
    if (mflagp[0])
      valid = ((const unsigned char*)mmask)[(size_t)g * CTX + tid] != 0;
    else
      valid = ((const unsigned int*)mmask)[(size_t)g * CTX + tid] != 0u;
    maskbias[tid] = valid ? 0.0f : -1e30f;
  }

  const float* vg = vmat + (size_t)g * (CTX * DV);
  short8 vb[2][4];
#pragma unroll
  for (int kt = 0; kt < 2; kt++)
#pragma unroll
    for (int nt = 0; nt < 4; nt++) {
      const int d = wave * 64 + nt * 16 + i16;
      const float* vcol = vg + (size_t)(kt * 32 + hi4 * 8) * DV + d;
      short8 t;
#pragma unroll
      for (int j = 0; j < 8; j++) t[j] = (short)f2bf_bits(vcol[(size_t)j * DV]);
      vb[kt][nt] = t;
    }

  __syncthreads();
  float mb[16];
#pragma unroll
  for (int mt = 0; mt < 4; mt++)
#pragma unroll
    for (int r = 0; r < 4; r++)
      mb[mt * 4 + r] = maskbias[mt * 16 + hi4 * 4 + r];

  const unsigned short* kzg = kz + (size_t)g * (CTX * DZ);
  const int nchunks = (q1 - q0 + 15) >> 4;

  for (int c = 0; c < nchunks; c++) {
    const int qbase = q0 + c * 16;
    f32x4 accs[4];
#pragma unroll
    for (int mt = 0; mt < 4; mt++) accs[mt] = {0.f, 0.f, 0.f, 0.f};

    int qrow = qbase + i16; if (qrow > NQ - 1) qrow = NQ - 1;
    const unsigned short* qh_p = qzh + (size_t)qrow * DZ;
    const unsigned short* ql_p = qzl + (size_t)qrow * DZ;
#pragma unroll
    for (int kk = 0; kk < DZ; kk += 32) {
      short8 bfh = *reinterpret_cast<const short8*>(qh_p + kk + hi4 * 8);
      short8 bfl = *reinterpret_cast<const short8*>(ql_p + kk + hi4 * 8);
#pragma unroll
      for (int mt = 0; mt < 4; mt++) {
        short8 af = *reinterpret_cast<const short8*>(kzg + (size_t)(mt * 16 + i16) * DZ + kk + hi4 * 8);
        accs[mt] = __builtin_amdgcn_mfma_f32_16x16x32_bf16(af, bfh, accs[mt], 0, 0, 0);
        accs[mt] = __builtin_amdgcn_mfma_f32_16x16x32_bf16(af, bfl, accs[mt], 0, 0, 0);
      }
    }

    float mx = -3.0e38f;
#pragma unroll
    for (int mt = 0; mt < 4; mt++)
#pragma unroll
      for (int r = 0; r < 4; r++) {
        float s = accs[mt][r] + mb[mt * 4 + r];
        accs[mt][r] = s;
        mx = fmaxf(mx, s);
      }
    mx = fmaxf(mx, __shfl_xor(mx, 16));
    mx = fmaxf(mx, __shfl_xor(mx, 32));
    float sum = 0.f;
#pragma unroll
    for (int mt = 0; mt < 4; mt++)
#pragma unroll
      for (int r = 0; r < 4; r++) {
        float p = __expf(accs[mt][r] - mx);
        accs[mt][r] = p;
        sum += p;
      }
    sum += __shfl_xor(sum, 16);
    sum += __shfl_xor(sum, 32);
    const float inv = 1.0f / sum;

    __syncthreads();
#pragma unroll
    for (int mt = 0; mt < 4; mt++)
#pragma unroll
      for (int r = 0; r < 4; r++) {
        const int mrow = mt * 16 + hi4 * 4 + r;
        unsigned short h, l; split2(accs[mt][r] * inv, h, l);
        ph_lds[mrow * 16 + i16] = h;
        pl_lds[mrow * 16 + i16] = l;
      }

    f32x4 acco[4];
#pragma unroll
    for (int nt = 0; nt < 4; nt++) acco[nt] = {0.f, 0.f, 0.f, 0.f};
#pragma unroll
    for (int kt = 0; kt < 2; kt++) {
      short8 pah, pal;
#pragma unroll
      for (int j = 0; j < 8; j++) {
        pah[j] = (short)ph_lds[(kt * 32 + hi4 * 8 + j) * 16 + i16];
        pal[j] = (short)pl_lds[(kt * 32 + hi4 * 8 + j) * 16 + i16];
      }
#pragma unroll
      for (int nt = 0; nt < 4; nt++) {
        acco[nt] = __builtin_amdgcn_mfma_f32_16x16x32_bf16(pah, vb[kt][nt], acco[nt], 0, 0, 0);
        acco[nt] = __builtin_amdgcn_mfma_f32_16x16x32_bf16(pal, vb[kt][nt], acco[nt], 0, 0, 0);
      }
    }

#pragma unroll
    for (int nt = 0; nt < 4; nt++) {
      const int d = wave * 64 + nt * 16 + i16;
#pragma unroll
      for (int r = 0; r < 4; r++) {
        const int qrow2 = qbase + hi4 * 4 + r;
        if (qrow2 < q1)
          out[(size_t)qrow2 * DV + d] = acco[nt][r];
      }
    }
  }
}

// ---------------- attn v2: pipelined S-loop, bounds(256,4), groups [1024,2048) ----------------
__global__ __launch_bounds__(256, 4) void attn_lite2_kernel(
    const unsigned short* __restrict__ kz, const float* __restrict__ vmat,
    const void* __restrict__ mmask, const int* __restrict__ mflagp,
    const int* __restrict__ starts,
    const unsigned short* __restrict__ qzh, const unsigned short* __restrict__ qzl,
    float* __restrict__ out, int gbase)
{
  const int g = gbase + blockIdx.x;
  const int q0 = starts[g];
  const int q1 = starts[g + 1];
  if (q0 >= q1) return;

  const int tid = threadIdx.x;
  const int wave = tid >> 6, lane = tid & 63;
  const int i16 = lane & 15, hi4 = lane >> 4;

  __shared__ __align__(16) unsigned short ph_lds[CTX * 16];
  __shared__ __align__(16) unsigned short pl_lds[CTX * 16];
  __shared__ float maskbias[CTX];

  if (tid < CTX) {
    bool valid;
    if (mflagp[0])
      valid = ((const unsigned char*)mmask)[(size_t)g * CTX + tid] != 0;
    else
      valid = ((const unsigned int*)mmask)[(size_t)g * CTX + tid] != 0u;
    maskbias[tid] = valid ? 0.0f : -1e30f;
  }

  const float* vg = vmat + (size_t)g * (CTX * DV);
  short8 vb[2][4];
#pragma unroll
  for (int kt = 0; kt < 2; kt++)
#pragma unroll
    for (int nt = 0; nt < 4; nt++) {
      const int d = wave * 64 + nt * 16 + i16;
      const float* vcol = vg + (size_t)(kt * 32 + hi4 * 8) * DV + d;
      short8 t;
#pragma unroll
      for (int j = 0; j < 8; j++) t[j] = (short)f2bf_bits(vcol[(size_t)j * DV]);
      vb[kt][nt] = t;
    }

  __syncthreads();
  float mb[16];
#pragma unroll
  for (int mt = 0; mt < 4; mt++)
#pragma unroll
    for (int r = 0; r < 4; r++)
      mb[mt * 4 + r] = maskbias[mt * 16 + hi4 * 4 + r];

  const unsigned short* kzg = kz + (size_t)g * (CTX * DZ);
  const int nchunks = (q1 - q0 + 15) >> 4;

  for (int c = 0; c < nchunks; c++) {
    const int qbase = q0 + c * 16;
    f32x4 accs[4];
#pragma unroll
    for (int mt = 0; mt < 4; mt++) accs[mt] = {0.f, 0.f, 0.f, 0.f};

    int qrow = qbase + i16; if (qrow > NQ - 1) qrow = NQ - 1;
    const unsigned short* qh_p = qzh + (size_t)qrow * DZ;
    const unsigned short* ql_p = qzl + (size_t)qrow * DZ;

    // prime kk=0
    short8 bfh = *reinterpret_cast<const short8*>(qh_p + hi4 * 8);
    short8 bfl = *reinterpret_cast<const short8*>(ql_p + hi4 * 8);
    short8 af[4];
#pragma unroll
    for (int mt = 0; mt < 4; mt++)
      af[mt] = *reinterpret_cast<const short8*>(kzg + (size_t)(mt * 16 + i16) * DZ + hi4 * 8);

#pragma unroll
    for (int it = 0; it < 8; it++) {
      short8 bfhn, bfln, afn[4];
      if (it < 7) {
        const int kk = (it + 1) * 32;
        bfhn = *reinterpret_cast<const short8*>(qh_p + kk + hi4 * 8);
        bfln = *reinterpret_cast<const short8*>(ql_p + kk + hi4 * 8);
#pragma unroll
        for (int mt = 0; mt < 4; mt++)
          afn[mt] = *reinterpret_cast<const short8*>(kzg + (size_t)(mt * 16 + i16) * DZ + kk + hi4 * 8);
      }
#pragma unroll
      for (int mt = 0; mt < 4; mt++) {
        accs[mt] = __builtin_amdgcn_mfma_f32_16x16x32_bf16(af[mt], bfh, accs[mt], 0, 0, 0);
        accs[mt] = __builtin_amdgcn_mfma_f32_16x16x32_bf16(af[mt], bfl, accs[mt], 0, 0, 0);
      }
      if (it < 7) {
        bfh = bfhn; bfl = bfln;
#pragma unroll
        for (int mt = 0; mt < 4; mt++) af[mt] = afn[mt];
      }
    }

    float mx = -3.0e38f;
#pragma unroll
    for (int mt = 0; mt < 4; mt++)
#pragma unroll
      for (int r = 0; r < 4; r++) {
        float s = accs[mt][r] + mb[mt * 4 + r];
        accs[mt][r] = s;
        mx = fmaxf(mx, s);
      }
    mx = fmaxf(mx, __shfl_xor(mx, 16));
    mx = fmaxf(mx, __shfl_xor(mx, 32));
    float sum = 0.f;
#pragma unroll
    for (int mt = 0; mt < 4; mt++)
#pragma unroll
      for (int r = 0; r < 4; r++) {
        float p = __expf(accs[mt][r] - mx);
        accs[mt][r] = p;
        sum += p;
      }
    sum += __shfl_xor(sum, 16);
    sum += __shfl_xor(sum, 32);
    const float inv = 1.0f / sum;

    __syncthreads();
#pragma unroll
    for (int mt = 0; mt < 4; mt++)
#pragma unroll
      for (int r = 0; r < 4; r++) {
        const int mrow = mt * 16 + hi4 * 4 + r;
        unsigned short h, l; split2(accs[mt][r] * inv, h, l);
        ph_lds[mrow * 16 + i16] = h;
        pl_lds[mrow * 16 + i16] = l;
      }

    f32x4 acco[4];
#pragma unroll
    for (int nt = 0; nt < 4; nt++) acco[nt] = {0.f, 0.f, 0.f, 0.f};
#pragma unroll
    for (int kt = 0; kt < 2; kt++) {
      short8 pah, pal;
#pragma unroll
      for (int j = 0; j < 8; j++) {
        pah[j] = (short)ph_lds[(kt * 32 + hi4 * 8 + j) * 16 + i16];
        pal[j] = (short)pl_lds[(kt * 32 + hi4 * 8 + j) * 16 + i16];
      }
#pragma unroll
      for (int nt = 0; nt < 4; nt++) {
        acco[nt] = __builtin_amdgcn_mfma_f32_16x16x32_bf16(pah, vb[kt][nt], acco[nt], 0, 0, 0);
        acco[nt] = __builtin_amdgcn_mfma_f32_16x16x32_bf16(pal, vb[kt][nt], acco[nt], 0, 0, 0);
      }
    }

#pragma unroll
    for (int nt = 0; nt < 4; nt++) {
      const int d = wave * 64 + nt * 16 + i16;
#pragma unroll
      for (int r = 0; r < 4; r++) {
        const int qrow2 = qbase + hi4 * 4 + r;
        if (qrow2 < q1)
          out[(size_t)qrow2 * DV + d] = acco[nt][r];
      }
    }
  }
}

// ---------------- fallback fused kernel (used only if ws too small) ----------------
__global__ __launch_bounds__(256, 3) void attn_fused_kernel(
    const float* __restrict__ kmat, const float* __restrict__ vmat,
    const void* __restrict__ mmask, const int* __restrict__ mflagp,
    const int* __restrict__ starts, const float* __restrict__ bk,
    const unsigned short* __restrict__ WkTh, const unsigned short* __restrict__ WkTl,
    const unsigned short* __restrict__ qzh, const unsigned short* __restrict__ qzl,
    float* __restrict__ out)
{
  const int g = blockIdx.x;
  const int q0 = starts[g];
  const int q1 = starts[g + 1];
  if (q0 >= q1) return;

  const int tid = threadIdx.x;
  const int wave = tid >> 6, lane = tid & 63;
  const int i16 = lane & 15, hi4 = lane >> 4;

  __shared__ __align__(16) unsigned short kz_lds[CTX * DZ];
  __shared__ __align__(16) unsigned short ph_lds[CTX * 16];
  __shared__ __align__(16) unsigned short pl_lds[CTX * 16];
  __shared__ float maskbias[CTX];

  if (tid < CTX) {
    bool valid;
    if (mflagp[0])
      valid = ((const unsigned char*)mmask)[(size_t)g * CTX + tid] != 0;
    else
      valid = ((const unsigned int*)mmask)[(size_t)g * CTX + tid] != 0u;
    maskbias[tid] = valid ? 0.0f : -1e30f;
  }

  const float* kg = kmat + (size_t)g * (CTX * DK);
  f32x4 acc[4][4];
#pragma unroll
  for (int a = 0; a < 4; a++)
#pragma unroll
    for (int b = 0; b < 4; b++) acc[a][b] = {0.f, 0.f, 0.f, 0.f};

  for (int kk = 0; kk < DK; kk += 32) {
    f32x4 araw[4][2];
#pragma unroll
    for (int mt = 0; mt < 4; mt++) {
      const float* src = kg + (mt * 16 + i16) * DK + kk + hi4 * 8;
      araw[mt][0] = *reinterpret_cast<const f32x4*>(src);
      araw[mt][1] = *reinterpret_cast<const f32x4*>(src + 4);
    }
    short8 ah[4];
#pragma unroll
    for (int mt = 0; mt < 4; mt++) ah[mt] = cvt8_h(araw[mt][0], araw[mt][1]);
#pragma unroll
    for (int ntp = 0; ntp < 2; ntp++) {
      short8 bh[2], bl[2];
#pragma unroll
      for (int j = 0; j < 2; j++) {
        const int n = wave * 64 + (ntp * 2 + j) * 16 + i16;
        bh[j] = *reinterpret_cast<const short8*>(WkTh + (size_t)n * DK + kk + hi4 * 8);
        bl[j] = *reinterpret_cast<const short8*>(WkTl + (size_t)n * DK + kk + hi4 * 8);
      }
#pragma unroll
      for (int mt = 0; mt < 4; mt++)
#pragma unroll
        for (int j = 0; j < 2; j++) {
          f32x4 a = acc[mt][ntp * 2 + j];
          a = __builtin_amdgcn_mfma_f32_16x16x32_bf16(ah[mt], bh[j], a, 0, 0, 0);
          a = __builtin_amdgcn_mfma_f32_16x16x32_bf16(ah[mt], bl[j], a, 0, 0, 0);
          acc[mt][ntp * 2 + j] = a;
        }
    }
  }

#pragma unroll
  for (int nt = 0; nt < 4; nt++) {
    const int n = wave * 64 + nt * 16 + i16;
    const float bias = bk[n];
#pragma unroll
    for (int mt = 0; mt < 4; mt++)
#pragma unroll
      for (int r = 0; r < 4; r++) {
        const int mrow = mt * 16 + hi4 * 4 + r;
        const int boff = (mrow * 512 + n * 2) ^ ((mrow & 7) << 4);
        *reinterpret_cast<unsigned short*>(reinterpret_cast<char*>(kz_lds) + boff)
            = f2bf_bits(acc[mt][nt][r] + bias);
      }
  }
  __syncthreads();

  float mb[16];
#pragma unroll
  for (int mt = 0; mt < 4; mt++)
#pragma unroll
    for (int r = 0; r < 4; r++)
      mb[mt * 4 + r] = maskbias[mt * 16 + hi4 * 4 + r];

  const float* vg = vmat + (size_t)g * (CTX * DV);
  const int nchunks = (q1 - q0 + 15) >> 4;

  for (int c = 0; c < nchunks; c++) {
    const int qbase = q0 + c * 16;
    f32x4 accs[4];
#pragma unroll
    for (int mt = 0; mt < 4; mt++) accs[mt] = {0.f, 0.f, 0.f, 0.f};

    int qrow = qbase + i16; if (qrow > NQ - 1) qrow = NQ - 1;
    const unsigned short* qh_p = qzh + (size_t)qrow * DZ;
    const unsigned short* ql_p = qzl + (size_t)qrow * DZ;
#pragma unroll
    for (int kk = 0; kk < DZ; kk += 32) {
      short8 bfh = *reinterpret_cast<const short8*>(qh_p + kk + hi4 * 8);
      short8 bfl = *reinterpret_cast<const short8*>(ql_p + kk + hi4 * 8);
#pragma unroll
      for (int mt = 0; mt < 4; mt++) {
        const int mrow = mt * 16 + i16;
        const int boff = (mrow * 512 + (kk + hi4 * 8) * 2) ^ ((mrow & 7) << 4);
        short8 afz = *reinterpret_cast<const short8*>(reinterpret_cast<const char*>(kz_lds) + boff);
        accs[mt] = __builtin_amdgcn_mfma_f32_16x16x32_bf16(afz, bfh, accs[mt], 0, 0, 0);
        accs[mt] = __builtin_amdgcn_mfma_f32_16x16x32_bf16(afz, bfl, accs[mt], 0, 0, 0);
      }
    }

    float mx = -3.0e38f;
#pragma unroll
    for (int mt = 0; mt < 4; mt++)
#pragma unroll
      for (int r = 0; r < 4; r++) {
        float s = accs[mt][r] + mb[mt * 4 + r];
        accs[mt][r] = s;
        mx = fmaxf(mx, s);
      }
    mx = fmaxf(mx, __shfl_xor(mx, 16));
    mx = fmaxf(mx, __shfl_xor(mx, 32));
    float sum = 0.f;
#pragma unroll
    for (int mt = 0; mt < 4; mt++)
#pragma unroll
      for (int r = 0; r < 4; r++) {
        float p = __expf(accs[mt][r] - mx);
        accs[mt][r] = p;
        sum += p;
      }
    sum += __shfl_xor(sum, 16);
    sum += __shfl_xor(sum, 32);
    const float inv = 1.0f / sum;

    __syncthreads();
#pragma unroll
    for (int mt = 0; mt < 4; mt++)
#pragma unroll
      for (int r = 0; r < 4; r++) {
        const int mrow = mt * 16 + hi4 * 4 + r;
        unsigned short h, l; split2(accs[mt][r] * inv, h, l);
        ph_lds[mrow * 16 + i16] = h;
        pl_lds[mrow * 16 + i16] = l;
      }

    f32x4 acco[4];
#pragma unroll
    for (int nt = 0; nt < 4; nt++) acco[nt] = {0.f, 0.f, 0.f, 0.f};
#pragma unroll
    for (int kt = 0; kt < 2; kt++) {
      short8 pah, pal;
#pragma unroll
      for (int j = 0; j < 8; j++) {
        pah[j] = (short)ph_lds[(kt * 32 + hi4 * 8 + j) * 16 + i16];
        pal[j] = (short)pl_lds[(kt * 32 + hi4 * 8 + j) * 16 + i16];
      }
#pragma unroll
      for (int nt = 0; nt < 4; nt++) {
        const int d = wave * 64 + nt * 16 + i16;
        const float* vcol = vg + (size_t)(kt * 32 + hi4 * 8) * DV + d;
        short8 vbf;
#pragma unroll
        for (int j = 0; j < 8; j++)
          vbf[j] = (short)f2bf_bits(vcol[(size_t)j * DV]);
        acco[nt] = __builtin_amdgcn_mfma_f32_16x16x32_bf16(pah, vbf, acco[nt], 0, 0, 0);
        acco[nt] = __builtin_amdgcn_mfma_f32_16x16x32_bf16(pal, vbf, acco[nt], 0, 0, 0);
      }
    }

#pragma unroll
    for (int nt = 0; nt < 4; nt++) {
      const int d = wave * 64 + nt * 16 + i16;
#pragma unroll
      for (int r = 0; r < 4; r++) {
        const int qrow2 = qbase + hi4 * 4 + r;
        if (qrow2 < q1)
          out[(size_t)qrow2 * DV + d] = acco[nt][r];
      }
    }
  }
}

extern "C" void kernel_launch(void* const* d_in, const int* in_sizes, int n_in,
                              void* d_out, int out_size, void* d_ws, size_t ws_size,
                              hipStream_t stream) {
  const float* q  = (const float*)d_in[0];
  const float* k  = (const float*)d_in[1];
  const float* v  = (const float*)d_in[2];
  const void*  m  = d_in[3];
  const int* gidx = (const int*)d_in[4];
  const float* Wq = (const float*)d_in[5];
  const float* bq = (const float*)d_in[6];
  const float* Wk = (const float*)d_in[7];
  const float* bk = (const float*)d_in[8];
  float* out = (float*)d_out;

  char* ws = (char*)d_ws;
  unsigned short* qzh  = (unsigned short*)(ws);                   // 4 MB
  unsigned short* qzl  = (unsigned short*)(ws + 4194304);         // 4 MB
  unsigned short* WqTh = (unsigned short*)(ws + 8388608);         // 256 KB
  unsigned short* WqTl = (unsigned short*)(ws + 8650752);         // 256 KB
  unsigned short* WkTh = (unsigned short*)(ws + 8912896);         // 128 KB
  unsigned short* WkTl = (unsigned short*)(ws + 9043968);         // 128 KB
  int* starts          = (int*)(ws + 9175040);                    // 2049*4
  int* mflag           = (int*)(ws + 9183240);                    // 4 B
  unsigned short* kz   = (unsigned short*)(ws + 9437184);         // 64 MiB
  const size_t NEED_SPLIT = 9437184ull + 67108864ull;

  hipLaunchKernelGGL(prep_kernel, dim3(777), dim3(256), 0, stream,
                     Wq, Wk, gidx, WqTh, WqTl, WkTh, WkTl, starts, mflag);
  hipLaunchKernelGGL(maskscan_kernel, dim3(128), dim3(256), 0, stream,
                     (const unsigned int*)m, mflag);
  hipLaunchKernelGGL(qz_kernel, dim3(NQ / 32), dim3(256), 0, stream,
                     q, bq, WqTh, WqTl, qzh, qzl);
  if (ws_size >= NEED_SPLIT) {
    // A/B: v1 on first half of rows, v2 (pipelined) on second half
    hipLaunchKernelGGL(kz_kernel, dim3(1024), dim3(256), 0, stream,
                       k, bk, WkTh, WkTl, kz);
    hipLaunchKernelGGL(kz2_kernel, dim3(2048), dim3(256), 0, stream,
                       k, bk, WkTh, WkTl, kz);
    // A/B: attn v1 on groups [0,1024), v2 (pipelined) on [1024,2048)
    hipLaunchKernelGGL(attn_lite_kernel, dim3(1024), dim3(256), 0, stream,
                       kz, v, m, (const int*)mflag, starts, qzh, qzl, out, 0);
    hipLaunchKernelGGL(attn_lite2_kernel, dim3(1024), dim3(256), 0, stream,
                       kz, v, m, (const int*)mflag, starts, qzh, qzl, out, 1024);
  } else {
    hipLaunchKernelGGL(attn_fused_kernel, dim3(NG), dim3(256), 0, stream,
                       k, v, m, (const int*)mflag, starts, bk, WkTh, WkTl, qzh, qzl, out);
  }
}

// Round 6
// 337.317 us; speedup vs baseline: 1.4505x; 1.4505x over previous
//
#include <hip/hip_runtime.h>
#include <hip/hip_bf16.h>

#define NQ 8192
#define NG 2048
#define CTX 64
#define DQ 512
#define DK 256
#define DV 256
#define DZ 256

typedef __attribute__((ext_vector_type(8))) short short8;
typedef __attribute__((ext_vector_type(4))) float f32x4;

__device__ __forceinline__ unsigned short f2bf_bits(float f) {
  __hip_bfloat16 h = __float2bfloat16(f);
  return __builtin_bit_cast(unsigned short, h);
}
__device__ __forceinline__ float bf2f(unsigned short u) {
  unsigned int x = ((unsigned int)u) << 16;
  return __builtin_bit_cast(float, x);
}
__device__ __forceinline__ void split2(float x, unsigned short& h, unsigned short& l) {
  h = f2bf_bits(x);
  l = f2bf_bits(x - bf2f(h));
}
__device__ __forceinline__ void cvt8_hl(f32x4 f0, f32x4 f1, short8& h8, short8& l8) {
#pragma unroll
  for (int j = 0; j < 4; j++) { unsigned short h, l; split2(f0[j], h, l); h8[j] = (short)h; l8[j] = (short)l; }
#pragma unroll
  for (int j = 0; j < 4; j++) { unsigned short h, l; split2(f1[j], h, l); h8[4 + j] = (short)h; l8[4 + j] = (short)l; }
}
__device__ __forceinline__ short8 cvt8_h(f32x4 f0, f32x4 f1) {
  short8 h8;
#pragma unroll
  for (int j = 0; j < 4; j++) h8[j] = (short)f2bf_bits(f0[j]);
#pragma unroll
  for (int j = 0; j < 4; j++) h8[4 + j] = (short)f2bf_bits(f1[j]);
  return h8;
}

// ---------------- prep: split+transpose weights, group ranges, flag init ----------------
__global__ void prep_kernel(const float* __restrict__ Wq, const float* __restrict__ Wk,
                            const int* __restrict__ gidx,
                            unsigned short* __restrict__ WqTh, unsigned short* __restrict__ WqTl,
                            unsigned short* __restrict__ WkTh, unsigned short* __restrict__ WkTl,
                            int* __restrict__ starts, int* __restrict__ mflag)
{
  int t = blockIdx.x * 256 + threadIdx.x;
  if (t < DZ * DQ) {                       // WqT*[z][kq] = Wq[kq][z]
    int z = t >> 9, kq = t & 511;
    unsigned short h, l; split2(Wq[(size_t)kq * DZ + z], h, l);
    WqTh[t] = h; WqTl[t] = l;
  } else if (t < DZ * DQ + DZ * DK) {      // WkT*[z][kx] = Wk[kx][z]
    int u = t - DZ * DQ;
    int z = u >> 8, kx = u & 255;
    unsigned short h, l; split2(Wk[(size_t)kx * DZ + z], h, l);
    WkTh[u] = h; WkTl[u] = l;
  } else if (t < DZ * DQ + DZ * DK + NG + 1) {
    int g = t - (DZ * DQ + DZ * DK);
    int lo = 0, hi = NQ;
    while (lo < hi) { int mid = (lo + hi) >> 1; if (gidx[mid] < g) lo = mid + 1; else hi = mid; }
    starts[g] = lo;
  } else if (t == DZ * DQ + DZ * DK + NG + 1) {
    mflag[0] = 0;
  }
}

// ---------------- mask dtype scan: flag=1 iff mask is 1-byte elements ----------------
__global__ void maskscan_kernel(const unsigned int* __restrict__ mw, int* __restrict__ flag)
{
  int i = blockIdx.x * 256 + threadIdx.x;
  unsigned int w = mw[i];
  bool bad = (w != 0u && w != 1u && w != 0x3F800000u);
  if (__any(bad) && ((threadIdx.x & 63) == 0))
    atomicOr(flag, 1);
}

// ---------------- convk: k f32 -> bf16 (hi), pure streaming ----------------
__global__ __launch_bounds__(256) void convk_kernel(
    const float* __restrict__ kmat, unsigned short* __restrict__ kh)
{
  const size_t total = (size_t)NG * CTX * DK;      // 33,554,432 elements
  const size_t stride = (size_t)gridDim.x * 256 * 8;
  for (size_t i = ((size_t)blockIdx.x * 256 + threadIdx.x) * 8; i < total; i += stride) {
    f32x4 f0 = *reinterpret_cast<const f32x4*>(kmat + i);
    f32x4 f1 = *reinterpret_cast<const f32x4*>(kmat + i + 4);
    *reinterpret_cast<short8*>(kh + i) = cvt8_h(f0, f1);
  }
}

// ---------------- qz = (q @ Wq + bq) * 1/16, stored as split bf16 pair ----------------
__global__ __launch_bounds__(256, 4) void qz_kernel(
    const float* __restrict__ q, const float* __restrict__ bq,
    const unsigned short* __restrict__ WqTh, const unsigned short* __restrict__ WqTl,
    unsigned short* __restrict__ qzh, unsigned short* __restrict__ qzl)
{
  const int tid = threadIdx.x;
  const int wave = tid >> 6, lane = tid & 63;
  const int i16 = lane & 15, hi4 = lane >> 4;
  const int mbase = blockIdx.x * 32;

  f32x4 acc[2][4];
#pragma unroll
  for (int a = 0; a < 2; a++)
#pragma unroll
    for (int b = 0; b < 4; b++) acc[a][b] = {0.f, 0.f, 0.f, 0.f};

  for (int kk = 0; kk < DQ; kk += 32) {
    f32x4 araw[2][2];
#pragma unroll
    for (int mt = 0; mt < 2; mt++) {
      const float* src = q + (size_t)(mbase + mt * 16 + i16) * DQ + kk + hi4 * 8;
      araw[mt][0] = *reinterpret_cast<const f32x4*>(src);
      araw[mt][1] = *reinterpret_cast<const f32x4*>(src + 4);
    }
    short8 ah[2], al[2];
#pragma unroll
    for (int mt = 0; mt < 2; mt++) cvt8_hl(araw[mt][0], araw[mt][1], ah[mt], al[mt]);

#pragma unroll
    for (int ntp = 0; ntp < 2; ntp++) {
      short8 bh[2], bl[2];
#pragma unroll
      for (int j = 0; j < 2; j++) {
        const int n = wave * 64 + (ntp * 2 + j) * 16 + i16;
        bh[j] = *reinterpret_cast<const short8*>(WqTh + (size_t)n * DQ + kk + hi4 * 8);
        bl[j] = *reinterpret_cast<const short8*>(WqTl + (size_t)n * DQ + kk + hi4 * 8);
      }
#pragma unroll
      for (int mt = 0; mt < 2; mt++)
#pragma unroll
        for (int j = 0; j < 2; j++) {
          f32x4 a = acc[mt][ntp * 2 + j];
          a = __builtin_amdgcn_mfma_f32_16x16x32_bf16(ah[mt], bh[j], a, 0, 0, 0);
          a = __builtin_amdgcn_mfma_f32_16x16x32_bf16(al[mt], bh[j], a, 0, 0, 0);
          a = __builtin_amdgcn_mfma_f32_16x16x32_bf16(ah[mt], bl[j], a, 0, 0, 0);
          acc[mt][ntp * 2 + j] = a;
        }
    }
  }

  const float scale = 0.0625f;
#pragma unroll
  for (int nt = 0; nt < 4; nt++) {
    const int n = wave * 64 + nt * 16 + i16;
    const float bias = bq[n];
#pragma unroll
    for (int mt = 0; mt < 2; mt++)
#pragma unroll
      for (int r = 0; r < 4; r++) {
        const int m = mbase + mt * 16 + hi4 * 4 + r;
        float x = (acc[mt][nt][r] + bias) * scale;
        unsigned short h, l; split2(x, h, l);
        qzh[(size_t)m * DZ + n] = h;
        qzl[(size_t)m * DZ + n] = l;
      }
  }
}

// ---------------- kz3: kz = kh @ Wk + bk, bf16 A direct, prefetch, in-place ok ----------------
__global__ __launch_bounds__(256, 3) void kz3_kernel(
    const unsigned short* __restrict__ kh, const float* __restrict__ bk,
    const unsigned short* __restrict__ WkTh, const unsigned short* __restrict__ WkTl,
    unsigned short* __restrict__ kz)   // kz may alias kh (rows read fully before written)
{
  const int tid = threadIdx.x;
  const int wave = tid >> 6, lane = tid & 63;
  const int i16 = lane & 15, hi4 = lane >> 4;
  const int mbase = blockIdx.x * 32;

  f32x4 acc[2][4];
#pragma unroll
  for (int a = 0; a < 2; a++)
#pragma unroll
    for (int b = 0; b < 4; b++) acc[a][b] = {0.f, 0.f, 0.f, 0.f};

  // prime step 0
  short8 a8[2], bh[4], bl[4];
#pragma unroll
  for (int mt = 0; mt < 2; mt++)
    a8[mt] = *reinterpret_cast<const short8*>(kh + (size_t)(mbase + mt * 16 + i16) * DK + hi4 * 8);
#pragma unroll
  for (int nt = 0; nt < 4; nt++) {
    const int n = wave * 64 + nt * 16 + i16;
    bh[nt] = *reinterpret_cast<const short8*>(WkTh + (size_t)n * DK + hi4 * 8);
    bl[nt] = *reinterpret_cast<const short8*>(WkTl + (size_t)n * DK + hi4 * 8);
  }

#pragma unroll
  for (int it = 0; it < 8; it++) {
    short8 a8n[2], bhn[4], bln[4];
    if (it < 7) {
      const int kk = (it + 1) * 32;
#pragma unroll
      for (int mt = 0; mt < 2; mt++)
        a8n[mt] = *reinterpret_cast<const short8*>(kh + (size_t)(mbase + mt * 16 + i16) * DK + kk + hi4 * 8);
#pragma unroll
      for (int nt = 0; nt < 4; nt++) {
        const int n = wave * 64 + nt * 16 + i16;
        bhn[nt] = *reinterpret_cast<const short8*>(WkTh + (size_t)n * DK + kk + hi4 * 8);
        bln[nt] = *reinterpret_cast<const short8*>(WkTl + (size_t)n * DK + kk + hi4 * 8);
      }
    }
#pragma unroll
    for (int mt = 0; mt < 2; mt++)
#pragma unroll
      for (int nt = 0; nt < 4; nt++) {
        f32x4 a = acc[mt][nt];
        a = __builtin_amdgcn_mfma_f32_16x16x32_bf16(a8[mt], bh[nt], a, 0, 0, 0);
        a = __builtin_amdgcn_mfma_f32_16x16x32_bf16(a8[mt], bl[nt], a, 0, 0, 0);
        acc[mt][nt] = a;
      }
    if (it < 7) {
#pragma unroll
      for (int mt = 0; mt < 2; mt++) a8[mt] = a8n[mt];
#pragma unroll
      for (int nt = 0; nt < 4; nt++) { bh[nt] = bhn[nt]; bl[nt] = bln[nt]; }
    }
  }

#pragma unroll
  for (int nt = 0; nt < 4; nt++) {
    const int n = wave * 64 + nt * 16 + i16;
    const float bias = bk[n];
#pragma unroll
    for (int mt = 0; mt < 2; mt++)
#pragma unroll
      for (int r = 0; r < 4; r++) {
        const int m = mbase + mt * 16 + hi4 * 4 + r;
        kz[(size_t)m * DZ + n] = f2bf_bits(acc[mt][nt][r] + bias);
      }
  }
}

// ---------------- attn: S from global kz, softmax, PV with v in regs ----------------
__global__ __launch_bounds__(256, 3) void attn_lite_kernel(
    const unsigned short* __restrict__ kz, const float* __restrict__ vmat,
    const void* __restrict__ mmask, const int* __restrict__ mflagp,
    const int* __restrict__ starts,
    const unsigned short* __restrict__ qzh, const unsigned short* __restrict__ qzl,
    float* __restrict__ out)
{
  const int g = blockIdx.x;
  const int q0 = starts[g];
  const int q1 = starts[g + 1];
  if (q0 >= q1) return;

  const int tid = threadIdx.x;
  const int wave = tid >> 6, lane = tid & 63;
  const int i16 = lane & 15, hi4 = lane >> 4;

  __shared__ __align__(16) unsigned short ph_lds[CTX * 16];
  __shared__ __align__(16) unsigned short pl_lds[CTX * 16];
  __shared__ float maskbias[CTX];

  if (tid < CTX) {
    bool valid;
    if (mflagp[0])
      valid = ((const unsigned char*)mmask)[(size_t)g * CTX + tid] != 0;
    else
      valid = ((const unsigned int*)mmask)[(size_t)g * CTX + tid] != 0u;
    maskbias[tid] = valid ? 0.0f : -1e30f;
  }

  const float* vg = vmat + (size_t)g * (CTX * DV);
  short8 vb[2][4];
#pragma unroll
  for (int kt = 0; kt < 2; kt++)
#pragma unroll
    for (int nt = 0; nt < 4; nt++) {
      const int d = wave * 64 + nt * 16 + i16;
      const float* vcol = vg + (size_t)(kt * 32 + hi4 * 8) * DV + d;
      short8 t;
#pragma unroll
      for (int j = 0; j < 8; j++) t[j] = (short)f2bf_bits(vcol[(size_t)j * DV]);
      vb[kt][nt] = t;
    }

  __syncthreads();
  float mb[16];
#pragma unroll
  for (int mt = 0; mt < 4; mt++)
#pragma unroll
    for (int r = 0; r < 4; r++)
      mb[mt * 4 + r] = maskbias[mt * 16 + hi4 * 4 + r];

  const unsigned short* kzg = kz + (size_t)g * (CTX * DZ);
  const int nchunks = (q1 - q0 + 15) >> 4;

  for (int c = 0; c < nchunks; c++) {
    const int qbase = q0 + c * 16;
    f32x4 accs[4];
#pragma unroll
    for (int mt = 0; mt < 4; mt++) accs[mt] = {0.f, 0.f, 0.f, 0.f};

    int qrow = qbase + i16; if (qrow > NQ - 1) qrow = NQ - 1;
    const unsigned short* qh_p = qzh + (size_t)qrow * DZ;
    const unsigned short* ql_p = qzl + (size_t)qrow * DZ;
#pragma unroll
    for (int kk = 0; kk < DZ; kk += 32) {
      short8 bfh = *reinterpret_cast<const short8*>(qh_p + kk + hi4 * 8);
      short8 bfl = *reinterpret_cast<const short8*>(ql_p + kk + hi4 * 8);
#pragma unroll
      for (int mt = 0; mt < 4; mt++) {
        short8 af = *reinterpret_cast<const short8*>(kzg + (size_t)(mt * 16 + i16) * DZ + kk + hi4 * 8);
        accs[mt] = __builtin_amdgcn_mfma_f32_16x16x32_bf16(af, bfh, accs[mt], 0, 0, 0);
        accs[mt] = __builtin_amdgcn_mfma_f32_16x16x32_bf16(af, bfl, accs[mt], 0, 0, 0);
      }
    }

    float mx = -3.0e38f;
#pragma unroll
    for (int mt = 0; mt < 4; mt++)
#pragma unroll
      for (int r = 0; r < 4; r++) {
        float s = accs[mt][r] + mb[mt * 4 + r];
        accs[mt][r] = s;
        mx = fmaxf(mx, s);
      }
    mx = fmaxf(mx, __shfl_xor(mx, 16));
    mx = fmaxf(mx, __shfl_xor(mx, 32));
    float sum = 0.f;
#pragma unroll
    for (int mt = 0; mt < 4; mt++)
#pragma unroll
      for (int r = 0; r < 4; r++) {
        float p = __expf(accs[mt][r] - mx);
        accs[mt][r] = p;
        sum += p;
      }
    sum += __shfl_xor(sum, 16);
    sum += __shfl_xor(sum, 32);
    const float inv = 1.0f / sum;

    __syncthreads();
#pragma unroll
    for (int mt = 0; mt < 4; mt++)
#pragma unroll
      for (int r = 0; r < 4; r++) {
        const int mrow = mt * 16 + hi4 * 4 + r;
        unsigned short h, l; split2(accs[mt][r] * inv, h, l);
        ph_lds[mrow * 16 + i16] = h;
        pl_lds[mrow * 16 + i16] = l;
      }

    f32x4 acco[4];
#pragma unroll
    for (int nt = 0; nt < 4; nt++) acco[nt] = {0.f, 0.f, 0.f, 0.f};
#pragma unroll
    for (int kt = 0; kt < 2; kt++) {
      short8 pah, pal;
#pragma unroll
      for (int j = 0; j < 8; j++) {
        pah[j] = (short)ph_lds[(kt * 32 + hi4 * 8 + j) * 16 + i16];
        pal[j] = (short)pl_lds[(kt * 32 + hi4 * 8 + j) * 16 + i16];
      }
#pragma unroll
      for (int nt = 0; nt < 4; nt++) {
        acco[nt] = __builtin_amdgcn_mfma_f32_16x16x32_bf16(pah, vb[kt][nt], acco[nt], 0, 0, 0);
        acco[nt] = __builtin_amdgcn_mfma_f32_16x16x32_bf16(pal, vb[kt][nt], acco[nt], 0, 0, 0);
      }
    }

#pragma unroll
    for (int nt = 0; nt < 4; nt++) {
      const int d = wave * 64 + nt * 16 + i16;
#pragma unroll
      for (int r = 0; r < 4; r++) {
        const int qrow2 = qbase + hi4 * 4 + r;
        if (qrow2 < q1)
          out[(size_t)qrow2 * DV + d] = acco[nt][r];
      }
    }
  }
}

// ---------------- fallback fused kernel (used only if ws too small) ----------------
__global__ __launch_bounds__(256, 3) void attn_fused_kernel(
    const float* __restrict__ kmat, const float* __restrict__ vmat,
    const void* __restrict__ mmask, const int* __restrict__ mflagp,
    const int* __restrict__ starts, const float* __restrict__ bk,
    const unsigned short* __restrict__ WkTh, const unsigned short* __restrict__ WkTl,
    const unsigned short* __restrict__ qzh, const unsigned short* __restrict__ qzl,
    float* __restrict__ out)
{
  const int g = blockIdx.x;
  const int q0 = starts[g];
  const int q1 = starts[g + 1];
  if (q0 >= q1) return;

  const int tid = threadIdx.x;
  const int wave = tid >> 6, lane = tid & 63;
  const int i16 = lane & 15, hi4 = lane >> 4;

  __shared__ __align__(16) unsigned short kz_lds[CTX * DZ];
  __shared__ __align__(16) unsigned short ph_lds[CTX * 16];
  __shared__ __align__(16) unsigned short pl_lds[CTX * 16];
  __shared__ float maskbias[CTX];

  if (tid < CTX) {
    bool valid;
    if (mflagp[0])
      valid = ((const unsigned char*)mmask)[(size_t)g * CTX + tid] != 0;
    else
      valid = ((const unsigned int*)mmask)[(size_t)g * CTX + tid] != 0u;
    maskbias[tid] = valid ? 0.0f : -1e30f;
  }

  const float* kg = kmat + (size_t)g * (CTX * DK);
  f32x4 acc[4][4];
#pragma unroll
  for (int a = 0; a < 4; a++)
#pragma unroll
    for (int b = 0; b < 4; b++) acc[a][b] = {0.f, 0.f, 0.f, 0.f};

  for (int kk = 0; kk < DK; kk += 32) {
    f32x4 araw[4][2];
#pragma unroll
    for (int mt = 0; mt < 4; mt++) {
      const float* src = kg + (mt * 16 + i16) * DK + kk + hi4 * 8;
      araw[mt][0] = *reinterpret_cast<const f32x4*>(src);
      araw[mt][1] = *reinterpret_cast<const f32x4*>(src + 4);
    }
    short8 ah[4];
#pragma unroll
    for (int mt = 0; mt < 4; mt++) ah[mt] = cvt8_h(araw[mt][0], araw[mt][1]);
#pragma unroll
    for (int ntp = 0; ntp < 2; ntp++) {
      short8 bh[2], bl[2];
#pragma unroll
      for (int j = 0; j < 2; j++) {
        const int n = wave * 64 + (ntp * 2 + j) * 16 + i16;
        bh[j] = *reinterpret_cast<const short8*>(WkTh + (size_t)n * DK + kk + hi4 * 8);
        bl[j] = *reinterpret_cast<const short8*>(WkTl + (size_t)n * DK + kk + hi4 * 8);
      }
#pragma unroll
      for (int mt = 0; mt < 4; mt++)
#pragma unroll
        for (int j = 0; j < 2; j++) {
          f32x4 a = acc[mt][ntp * 2 + j];
          a = __builtin_amdgcn_mfma_f32_16x16x32_bf16(ah[mt], bh[j], a, 0, 0, 0);
          a = __builtin_amdgcn_mfma_f32_16x16x32_bf16(ah[mt], bl[j], a, 0, 0, 0);
          acc[mt][ntp * 2 + j] = a;
        }
    }
  }

#pragma unroll
  for (int nt = 0; nt < 4; nt++) {
    const int n = wave * 64 + nt * 16 + i16;
    const float bias = bk[n];
#pragma unroll
    for (int mt = 0; mt < 4; mt++)
#pragma unroll
      for (int r = 0; r < 4; r++) {
        const int mrow = mt * 16 + hi4 * 4 + r;
        const int boff = (mrow * 512 + n * 2) ^ ((mrow & 7) << 4);
        *reinterpret_cast<unsigned short*>(reinterpret_cast<char*>(kz_lds) + boff)
            = f2bf_bits(acc[mt][nt][r] + bias);
      }
  }
  __syncthreads();

  float mb[16];
#pragma unroll
  for (int mt = 0; mt < 4; mt++)
#pragma unroll
    for (int r = 0; r < 4; r++)
      mb[mt * 4 + r] = maskbias[mt * 16 + hi4 * 4 + r];

  const float* vg = vmat + (size_t)g * (CTX * DV);
  const int nchunks = (q1 - q0 + 15) >> 4;

  for (int c = 0; c < nchunks; c++) {
    const int qbase = q0 + c * 16;
    f32x4 accs[4];
#pragma unroll
    for (int mt = 0; mt < 4; mt++) accs[mt] = {0.f, 0.f, 0.f, 0.f};

    int qrow = qbase + i16; if (qrow > NQ - 1) qrow = NQ - 1;
    const unsigned short* qh_p = qzh + (size_t)qrow * DZ;
    const unsigned short* ql_p = qzl + (size_t)qrow * DZ;
#pragma unroll
    for (int kk = 0; kk < DZ; kk += 32) {
      short8 bfh = *reinterpret_cast<const short8*>(qh_p + kk + hi4 * 8);
      short8 bfl = *reinterpret_cast<const short8*>(ql_p + kk + hi4 * 8);
#pragma unroll
      for (int mt = 0; mt < 4; mt++) {
        const int mrow = mt * 16 + i16;
        const int boff = (mrow * 512 + (kk + hi4 * 8) * 2) ^ ((mrow & 7) << 4);
        short8 afz = *reinterpret_cast<const short8*>(reinterpret_cast<const char*>(kz_lds) + boff);
        accs[mt] = __builtin_amdgcn_mfma_f32_16x16x32_bf16(afz, bfh, accs[mt], 0, 0, 0);
        accs[mt] = __builtin_amdgcn_mfma_f32_16x16x32_bf16(afz, bfl, accs[mt], 0, 0, 0);
      }
    }

    float mx = -3.0e38f;
#pragma unroll
    for (int mt = 0; mt < 4; mt++)
#pragma unroll
      for (int r = 0; r < 4; r++) {
        float s = accs[mt][r] + mb[mt * 4 + r];
        accs[mt][r] = s;
        mx = fmaxf(mx, s);
      }
    mx = fmaxf(mx, __shfl_xor(mx, 16));
    mx = fmaxf(mx, __shfl_xor(mx, 32));
    float sum = 0.f;
#pragma unroll
    for (int mt = 0; mt < 4; mt++)
#pragma unroll
      for (int r = 0; r < 4; r++) {
        float p = __expf(accs[mt][r] - mx);
        accs[mt][r] = p;
        sum += p;
      }
    sum += __shfl_xor(sum, 16);
    sum += __shfl_xor(sum, 32);
    const float inv = 1.0f / sum;

    __syncthreads();
#pragma unroll
    for (int mt = 0; mt < 4; mt++)
#pragma unroll
      for (int r = 0; r < 4; r++) {
        const int mrow = mt * 16 + hi4 * 4 + r;
        unsigned short h, l; split2(accs[mt][r] * inv, h, l);
        ph_lds[mrow * 16 + i16] = h;
        pl_lds[mrow * 16 + i16] = l;
      }

    f32x4 acco[4];
#pragma unroll
    for (int nt = 0; nt < 4; nt++) acco[nt] = {0.f, 0.f, 0.f, 0.f};
#pragma unroll
    for (int kt = 0; kt < 2; kt++) {
      short8 pah, pal;
#pragma unroll
      for (int j = 0; j < 8; j++) {
        pah[j] = (short)ph_lds[(kt * 32 + hi4 * 8 + j) * 16 + i16];
        pal[j] = (short)pl_lds[(kt * 32 + hi4 * 8 + j) * 16 + i16];
      }
#pragma unroll
      for (int nt = 0; nt < 4; nt++) {
        const int d = wave * 64 + nt * 16 + i16;
        const float* vcol = vg + (size_t)(kt * 32 + hi4 * 8) * DV + d;
        short8 vbf;
#pragma unroll
        for (int j = 0; j < 8; j++)
          vbf[j] = (short)f2bf_bits(vcol[(size_t)j * DV]);
        acco[nt] = __builtin_amdgcn_mfma_f32_16x16x32_bf16(pah, vbf, acco[nt], 0, 0, 0);
        acco[nt] = __builtin_amdgcn_mfma_f32_16x16x32_bf16(pal, vbf, acco[nt], 0, 0, 0);
      }
    }

#pragma unroll
    for (int nt = 0; nt < 4; nt++) {
      const int d = wave * 64 + nt * 16 + i16;
#pragma unroll
      for (int r = 0; r < 4; r++) {
        const int qrow2 = qbase + hi4 * 4 + r;
        if (qrow2 < q1)
          out[(size_t)qrow2 * DV + d] = acco[nt][r];
      }
    }
  }
}

extern "C" void kernel_launch(void* const* d_in, const int* in_sizes, int n_in,
                              void* d_out, int out_size, void* d_ws, size_t ws_size,
                              hipStream_t stream) {
  const float* q  = (const float*)d_in[0];
  const float* k  = (const float*)d_in[1];
  const float* v  = (const float*)d_in[2];
  const void*  m  = d_in[3];
  const int* gidx = (const int*)d_in[4];
  const float* Wq = (const float*)d_in[5];
  const float* bq = (const float*)d_in[6];
  const float* Wk = (const float*)d_in[7];
  const float* bk = (const float*)d_in[8];
  float* out = (float*)d_out;

  char* ws = (char*)d_ws;
  unsigned short* qzh  = (unsigned short*)(ws);                   // 4 MB
  unsigned short* qzl  = (unsigned short*)(ws + 4194304);         // 4 MB
  unsigned short* WqTh = (unsigned short*)(ws + 8388608);         // 256 KB
  unsigned short* WqTl = (unsigned short*)(ws + 8650752);         // 256 KB
  unsigned short* WkTh = (unsigned short*)(ws + 8912896);         // 128 KB
  unsigned short* WkTl = (unsigned short*)(ws + 9043968);         // 128 KB
  int* starts          = (int*)(ws + 9175040);                    // 2049*4
  int* mflag           = (int*)(ws + 9183240);                    // 4 B
  unsigned short* kh   = (unsigned short*)(ws + 9437184);         // 64 MiB (kh, then kz in-place)
  const size_t NEED_SPLIT = 9437184ull + 67108864ull;

  hipLaunchKernelGGL(prep_kernel, dim3(777), dim3(256), 0, stream,
                     Wq, Wk, gidx, WqTh, WqTl, WkTh, WkTl, starts, mflag);
  hipLaunchKernelGGL(maskscan_kernel, dim3(128), dim3(256), 0, stream,
                     (const unsigned int*)m, mflag);
  hipLaunchKernelGGL(qz_kernel, dim3(NQ / 32), dim3(256), 0, stream,
                     q, bq, WqTh, WqTl, qzh, qzl);
  if (ws_size >= NEED_SPLIT) {
    hipLaunchKernelGGL(convk_kernel, dim3(2048), dim3(256), 0, stream,
                       k, kh);
    hipLaunchKernelGGL(kz3_kernel, dim3(NG * CTX / 32), dim3(256), 0, stream,
                       kh, bk, WkTh, WkTl, kh /* in-place: kz aliases kh */);
    hipLaunchKernelGGL(attn_lite_kernel, dim3(NG), dim3(256), 0, stream,
                       kh, v, m, (const int*)mflag, starts, qzh, qzl, out);
  } else {
    hipLaunchKernelGGL(attn_fused_kernel, dim3(NG), dim3(256), 0, stream,
                       k, v, m, (const int*)mflag, starts, bk, WkTh, WkTl, qzh, qzl, out);
  }
}

// Round 7
// 115.595 us; speedup vs baseline: 4.2328x; 2.9181x over previous
//
#include <hip/hip_runtime.h>
#include <hip/hip_bf16.h>

#define NQ 8192
#define NG 2048
#define CTX 64
#define DQ 512
#define DK 256
#define DV 256
#define DZ 256

typedef __attribute__((ext_vector_type(8))) short short8;
typedef __attribute__((ext_vector_type(4))) float f32x4;

__device__ __forceinline__ unsigned short f2bf_bits(float f) {
  __hip_bfloat16 h = __float2bfloat16(f);
  return __builtin_bit_cast(unsigned short, h);
}
__device__ __forceinline__ float bf2f(unsigned short u) {
  unsigned int x = ((unsigned int)u) << 16;
  return __builtin_bit_cast(float, x);
}
__device__ __forceinline__ void split2(float x, unsigned short& h, unsigned short& l) {
  h = f2bf_bits(x);
  l = f2bf_bits(x - bf2f(h));
}
__device__ __forceinline__ void cvt8_hl(f32x4 f0, f32x4 f1, short8& h8, short8& l8) {
#pragma unroll
  for (int j = 0; j < 4; j++) { unsigned short h, l; split2(f0[j], h, l); h8[j] = (short)h; l8[j] = (short)l; }
#pragma unroll
  for (int j = 0; j < 4; j++) { unsigned short h, l; split2(f1[j], h, l); h8[4 + j] = (short)h; l8[4 + j] = (short)l; }
}
__device__ __forceinline__ short8 cvt8_h(f32x4 f0, f32x4 f1) {
  short8 h8;
#pragma unroll
  for (int j = 0; j < 4; j++) h8[j] = (short)f2bf_bits(f0[j]);
#pragma unroll
  for (int j = 0; j < 4; j++) h8[4 + j] = (short)f2bf_bits(f1[j]);
  return h8;
}

// ---------------- prep: WqT split (transposed), Wk split (straight), starts, flag ----------------
__global__ void prep_kernel(const float* __restrict__ Wq, const float* __restrict__ Wk,
                            const int* __restrict__ gidx,
                            unsigned short* __restrict__ WqTh, unsigned short* __restrict__ WqTl,
                            unsigned short* __restrict__ Wkh, unsigned short* __restrict__ Wkl,
                            int* __restrict__ starts, int* __restrict__ mflag)
{
  int t = blockIdx.x * 256 + threadIdx.x;
  if (t < DZ * DQ) {                       // WqT*[z][kq] = Wq[kq][z]
    int z = t >> 9, kq = t & 511;
    unsigned short h, l; split2(Wq[(size_t)kq * DZ + z], h, l);
    WqTh[t] = h; WqTl[t] = l;
  } else if (t < DZ * DQ + DK * DZ) {      // Wk split in original layout [x][z]
    int u = t - DZ * DQ;
    unsigned short h, l; split2(Wk[u], h, l);
    Wkh[u] = h; Wkl[u] = l;
  } else if (t < DZ * DQ + DK * DZ + NG + 1) {
    int g = t - (DZ * DQ + DK * DZ);
    int lo = 0, hi = NQ;
    while (lo < hi) { int mid = (lo + hi) >> 1; if (gidx[mid] < g) lo = mid + 1; else hi = mid; }
    starts[g] = lo;
  } else if (t == DZ * DQ + DK * DZ + NG + 1) {
    mflag[0] = 0;
  }
}

// ---------------- mask dtype scan: flag=1 iff mask is 1-byte elements ----------------
__global__ void maskscan_kernel(const unsigned int* __restrict__ mw, int* __restrict__ flag)
{
  int i = blockIdx.x * 256 + threadIdx.x;
  unsigned int w = mw[i];
  bool bad = (w != 0u && w != 1u && w != 0x3F800000u);
  if (__any(bad) && ((threadIdx.x & 63) == 0))
    atomicOr(flag, 1);
}

// ---------------- qz = (q @ Wq + bq) * 1/16, stored as split bf16 pair ----------------
__global__ __launch_bounds__(256, 4) void qz_kernel(
    const float* __restrict__ q, const float* __restrict__ bq,
    const unsigned short* __restrict__ WqTh, const unsigned short* __restrict__ WqTl,
    unsigned short* __restrict__ qzh, unsigned short* __restrict__ qzl)
{
  const int tid = threadIdx.x;
  const int wave = tid >> 6, lane = tid & 63;
  const int i16 = lane & 15, hi4 = lane >> 4;
  const int mbase = blockIdx.x * 32;

  f32x4 acc[2][4];
#pragma unroll
  for (int a = 0; a < 2; a++)
#pragma unroll
    for (int b = 0; b < 4; b++) acc[a][b] = {0.f, 0.f, 0.f, 0.f};

  for (int kk = 0; kk < DQ; kk += 32) {
    f32x4 araw[2][2];
#pragma unroll
    for (int mt = 0; mt < 2; mt++) {
      const float* src = q + (size_t)(mbase + mt * 16 + i16) * DQ + kk + hi4 * 8;
      araw[mt][0] = *reinterpret_cast<const f32x4*>(src);
      araw[mt][1] = *reinterpret_cast<const f32x4*>(src + 4);
    }
    short8 ah[2], al[2];
#pragma unroll
    for (int mt = 0; mt < 2; mt++) cvt8_hl(araw[mt][0], araw[mt][1], ah[mt], al[mt]);

#pragma unroll
    for (int ntp = 0; ntp < 2; ntp++) {
      short8 bh[2], bl[2];
#pragma unroll
      for (int j = 0; j < 2; j++) {
        const int n = wave * 64 + (ntp * 2 + j) * 16 + i16;
        bh[j] = *reinterpret_cast<const short8*>(WqTh + (size_t)n * DQ + kk + hi4 * 8);
        bl[j] = *reinterpret_cast<const short8*>(WqTl + (size_t)n * DQ + kk + hi4 * 8);
      }
#pragma unroll
      for (int mt = 0; mt < 2; mt++)
#pragma unroll
        for (int j = 0; j < 2; j++) {
          f32x4 a = acc[mt][ntp * 2 + j];
          a = __builtin_amdgcn_mfma_f32_16x16x32_bf16(ah[mt], bh[j], a, 0, 0, 0);
          a = __builtin_amdgcn_mfma_f32_16x16x32_bf16(al[mt], bh[j], a, 0, 0, 0);
          a = __builtin_amdgcn_mfma_f32_16x16x32_bf16(ah[mt], bl[j], a, 0, 0, 0);
          acc[mt][ntp * 2 + j] = a;
        }
    }
  }

  const float scale = 0.0625f;
#pragma unroll
  for (int nt = 0; nt < 4; nt++) {
    const int n = wave * 64 + nt * 16 + i16;
    const float bias = bq[n];
#pragma unroll
    for (int mt = 0; mt < 2; mt++)
#pragma unroll
      for (int r = 0; r < 4; r++) {
        const int m = mbase + mt * 16 + hi4 * 4 + r;
        float x = (acc[mt][nt][r] + bias) * scale;
        unsigned short h, l; split2(x, h, l);
        qzh[(size_t)m * DZ + n] = h;
        qzl[(size_t)m * DZ + n] = l;
      }
  }
}

// ---------------- qk = qz @ Wk^T (3-term split), stored as split bf16 pair ----------------
// qk[q][x] = sum_z qz[q][z] * Wk[x][z]   (bk dropped: per-query constant cancels in softmax)
__global__ __launch_bounds__(256, 4) void qk_kernel(
    const unsigned short* __restrict__ qzh, const unsigned short* __restrict__ qzl,
    const unsigned short* __restrict__ Wkh, const unsigned short* __restrict__ Wkl,
    unsigned short* __restrict__ qkh, unsigned short* __restrict__ qkl)
{
  const int tid = threadIdx.x;
  const int wave = tid >> 6, lane = tid & 63;
  const int i16 = lane & 15, hi4 = lane >> 4;
  const int mbase = blockIdx.x * 32;

  f32x4 acc[2][4];
#pragma unroll
  for (int a = 0; a < 2; a++)
#pragma unroll
    for (int b = 0; b < 4; b++) acc[a][b] = {0.f, 0.f, 0.f, 0.f};

#pragma unroll
  for (int kk = 0; kk < DZ; kk += 32) {
    short8 ah[2], al[2];
#pragma unroll
    for (int mt = 0; mt < 2; mt++) {
      ah[mt] = *reinterpret_cast<const short8*>(qzh + (size_t)(mbase + mt * 16 + i16) * DZ + kk + hi4 * 8);
      al[mt] = *reinterpret_cast<const short8*>(qzl + (size_t)(mbase + mt * 16 + i16) * DZ + kk + hi4 * 8);
    }
#pragma unroll
    for (int ntp = 0; ntp < 2; ntp++) {
      short8 bh[2], bl[2];
#pragma unroll
      for (int j = 0; j < 2; j++) {
        const int n = wave * 64 + (ntp * 2 + j) * 16 + i16;   // x index (row of Wk)
        bh[j] = *reinterpret_cast<const short8*>(Wkh + (size_t)n * DZ + kk + hi4 * 8);
        bl[j] = *reinterpret_cast<const short8*>(Wkl + (size_t)n * DZ + kk + hi4 * 8);
      }
#pragma unroll
      for (int mt = 0; mt < 2; mt++)
#pragma unroll
        for (int j = 0; j < 2; j++) {
          f32x4 a = acc[mt][ntp * 2 + j];
          a = __builtin_amdgcn_mfma_f32_16x16x32_bf16(ah[mt], bh[j], a, 0, 0, 0);
          a = __builtin_amdgcn_mfma_f32_16x16x32_bf16(al[mt], bh[j], a, 0, 0, 0);
          a = __builtin_amdgcn_mfma_f32_16x16x32_bf16(ah[mt], bl[j], a, 0, 0, 0);
          acc[mt][ntp * 2 + j] = a;
        }
    }
  }

#pragma unroll
  for (int nt = 0; nt < 4; nt++) {
    const int n = wave * 64 + nt * 16 + i16;
#pragma unroll
    for (int mt = 0; mt < 2; mt++)
#pragma unroll
      for (int r = 0; r < 4; r++) {
        const int mrow = mbase + mt * 16 + hi4 * 4 + r;
        unsigned short h, l; split2(acc[mt][nt][r], h, l);
        qkh[(size_t)mrow * DK + n] = h;
        qkl[(size_t)mrow * DK + n] = l;
      }
  }
}

// ---------------- attn: stage k[g] bf16 in LDS, S = k*qk, softmax, PV ----------------
__global__ __launch_bounds__(256, 3) void attn_qk_kernel(
    const float* __restrict__ kmat, const float* __restrict__ vmat,
    const void* __restrict__ mmask, const int* __restrict__ mflagp,
    const int* __restrict__ starts,
    const unsigned short* __restrict__ qkh, const unsigned short* __restrict__ qkl,
    float* __restrict__ out)
{
  const int g = blockIdx.x;
  const int q0 = starts[g];
  const int q1 = starts[g + 1];
  if (q0 >= q1) return;

  const int tid = threadIdx.x;
  const int wave = tid >> 6, lane = tid & 63;
  const int i16 = lane & 15, hi4 = lane >> 4;

  __shared__ __align__(16) unsigned short k_lds[CTX * DK];   // 32 KB, XOR-swizzled rows
  __shared__ __align__(16) unsigned short ph_lds[CTX * 16];  // 2 KB
  __shared__ __align__(16) unsigned short pl_lds[CTX * 16];  // 2 KB
  __shared__ float maskbias[CTX];

  if (tid < CTX) {
    bool valid;
    if (mflagp[0])
      valid = ((const unsigned char*)mmask)[(size_t)g * CTX + tid] != 0;
    else
      valid = ((const unsigned int*)mmask)[(size_t)g * CTX + tid] != 0u;
    maskbias[tid] = valid ? 0.0f : -1e30f;
  }

  // ---- stage k[g] (64x256 f32) -> bf16 LDS, swizzled
  const float* kg = kmat + (size_t)g * (CTX * DK);
#pragma unroll
  for (int it = 0; it < 8; it++) {
    const int flat = it * 2048 + tid * 8;
    const int row = flat >> 8, col = flat & 255;
    f32x4 f0 = *reinterpret_cast<const f32x4*>(kg + flat);
    f32x4 f1 = *reinterpret_cast<const f32x4*>(kg + flat + 4);
    short8 h8 = cvt8_h(f0, f1);
    const int boff = (row * 512 + col * 2) ^ ((row & 7) << 4);
    *reinterpret_cast<short8*>(reinterpret_cast<char*>(k_lds) + boff) = h8;
  }

  // ---- preload v slice to regs (chunk-invariant)
  const float* vg = vmat + (size_t)g * (CTX * DV);
  short8 vb[2][4];
#pragma unroll
  for (int kt = 0; kt < 2; kt++)
#pragma unroll
    for (int nt = 0; nt < 4; nt++) {
      const int d = wave * 64 + nt * 16 + i16;
      const float* vcol = vg + (size_t)(kt * 32 + hi4 * 8) * DV + d;
      short8 t;
#pragma unroll
      for (int j = 0; j < 8; j++) t[j] = (short)f2bf_bits(vcol[(size_t)j * DV]);
      vb[kt][nt] = t;
    }

  __syncthreads();
  float mb[16];
#pragma unroll
  for (int mt = 0; mt < 4; mt++)
#pragma unroll
    for (int r = 0; r < 4; r++)
      mb[mt * 4 + r] = maskbias[mt * 16 + hi4 * 4 + r];

  const int nchunks = (q1 - q0 + 15) >> 4;

  for (int c = 0; c < nchunks; c++) {
    const int qbase = q0 + c * 16;
    f32x4 accs[4];
#pragma unroll
    for (int mt = 0; mt < 4; mt++) accs[mt] = {0.f, 0.f, 0.f, 0.f};

    int qrow = qbase + i16; if (qrow > NQ - 1) qrow = NQ - 1;  // clamp (masked at store)
    const unsigned short* qh_p = qkh + (size_t)qrow * DK;
    const unsigned short* ql_p = qkl + (size_t)qrow * DK;
#pragma unroll
    for (int kk = 0; kk < DK; kk += 32) {
      short8 bfh = *reinterpret_cast<const short8*>(qh_p + kk + hi4 * 8);
      short8 bfl = *reinterpret_cast<const short8*>(ql_p + kk + hi4 * 8);
#pragma unroll
      for (int mt = 0; mt < 4; mt++) {
        const int mrow = mt * 16 + i16;
        const int boff = (mrow * 512 + (kk + hi4 * 8) * 2) ^ ((mrow & 7) << 4);
        short8 af = *reinterpret_cast<const short8*>(reinterpret_cast<const char*>(k_lds) + boff);
        accs[mt] = __builtin_amdgcn_mfma_f32_16x16x32_bf16(af, bfh, accs[mt], 0, 0, 0);
        accs[mt] = __builtin_amdgcn_mfma_f32_16x16x32_bf16(af, bfl, accs[mt], 0, 0, 0);
      }
    }

    // mask + softmax over 64 ctx rows (per query column i16)
    float mx = -3.0e38f;
#pragma unroll
    for (int mt = 0; mt < 4; mt++)
#pragma unroll
      for (int r = 0; r < 4; r++) {
        float s = accs[mt][r] + mb[mt * 4 + r];
        accs[mt][r] = s;
        mx = fmaxf(mx, s);
      }
    mx = fmaxf(mx, __shfl_xor(mx, 16));
    mx = fmaxf(mx, __shfl_xor(mx, 32));
    float sum = 0.f;
#pragma unroll
    for (int mt = 0; mt < 4; mt++)
#pragma unroll
      for (int r = 0; r < 4; r++) {
        float p = __expf(accs[mt][r] - mx);
        accs[mt][r] = p;
        sum += p;
      }
    sum += __shfl_xor(sum, 16);
    sum += __shfl_xor(sum, 32);
    const float inv = 1.0f / sum;

    __syncthreads();  // all waves done reading p_lds of previous chunk
#pragma unroll
    for (int mt = 0; mt < 4; mt++)
#pragma unroll
      for (int r = 0; r < 4; r++) {
        const int mrow = mt * 16 + hi4 * 4 + r;
        unsigned short h, l; split2(accs[mt][r] * inv, h, l);
        ph_lds[mrow * 16 + i16] = h;
        pl_lds[mrow * 16 + i16] = l;
      }

    // PV: out_chunk(16 x 256) = P (16x64) @ v[g] (64x256); waves split d
    f32x4 acco[4];
#pragma unroll
    for (int nt = 0; nt < 4; nt++) acco[nt] = {0.f, 0.f, 0.f, 0.f};
#pragma unroll
    for (int kt = 0; kt < 2; kt++) {
      short8 pah, pal;
#pragma unroll
      for (int j = 0; j < 8; j++) {
        pah[j] = (short)ph_lds[(kt * 32 + hi4 * 8 + j) * 16 + i16];
        pal[j] = (short)pl_lds[(kt * 32 + hi4 * 8 + j) * 16 + i16];
      }
#pragma unroll
      for (int nt = 0; nt < 4; nt++) {
        acco[nt] = __builtin_amdgcn_mfma_f32_16x16x32_bf16(pah, vb[kt][nt], acco[nt], 0, 0, 0);
        acco[nt] = __builtin_amdgcn_mfma_f32_16x16x32_bf16(pal, vb[kt][nt], acco[nt], 0, 0, 0);
      }
    }

#pragma unroll
    for (int nt = 0; nt < 4; nt++) {
      const int d = wave * 64 + nt * 16 + i16;
#pragma unroll
      for (int r = 0; r < 4; r++) {
        const int qrow2 = qbase + hi4 * 4 + r;
        if (qrow2 < q1)
          out[(size_t)qrow2 * DV + d] = acco[nt][r];
      }
    }
  }
}

extern "C" void kernel_launch(void* const* d_in, const int* in_sizes, int n_in,
                              void* d_out, int out_size, void* d_ws, size_t ws_size,
                              hipStream_t stream) {
  const float* q  = (const float*)d_in[0];
  const float* k  = (const float*)d_in[1];
  const float* v  = (const float*)d_in[2];
  const void*  m  = d_in[3];
  const int* gidx = (const int*)d_in[4];
  const float* Wq = (const float*)d_in[5];
  const float* bq = (const float*)d_in[6];
  // Wk used via prep; bk dropped (per-query constant, cancels in softmax)
  const float* Wk = (const float*)d_in[7];
  float* out = (float*)d_out;

  char* ws = (char*)d_ws;
  unsigned short* qzh  = (unsigned short*)(ws);                   // 4 MB
  unsigned short* qzl  = (unsigned short*)(ws + 4194304);         // 4 MB
  unsigned short* qkh  = (unsigned short*)(ws + 8388608);         // 4 MB
  unsigned short* qkl  = (unsigned short*)(ws + 12582912);        // 4 MB
  unsigned short* WqTh = (unsigned short*)(ws + 16777216);        // 256 KB
  unsigned short* WqTl = (unsigned short*)(ws + 17039360);        // 256 KB
  unsigned short* Wkh  = (unsigned short*)(ws + 17301504);        // 128 KB
  unsigned short* Wkl  = (unsigned short*)(ws + 17432576);        // 128 KB
  int* starts          = (int*)(ws + 17563648);                   // 2049*4
  int* mflag           = (int*)(ws + 17571844);                   // 4 B

  hipLaunchKernelGGL(prep_kernel, dim3(777), dim3(256), 0, stream,
                     Wq, Wk, gidx, WqTh, WqTl, Wkh, Wkl, starts, mflag);
  hipLaunchKernelGGL(maskscan_kernel, dim3(128), dim3(256), 0, stream,
                     (const unsigned int*)m, mflag);
  hipLaunchKernelGGL(qz_kernel, dim3(NQ / 32), dim3(256), 0, stream,
                     q, bq, WqTh, WqTl, qzh, qzl);
  hipLaunchKernelGGL(qk_kernel, dim3(NQ / 32), dim3(256), 0, stream,
                     qzh, qzl, Wkh, Wkl, qkh, qkl);
  hipLaunchKernelGGL(attn_qk_kernel, dim3(NG), dim3(256), 0, stream,
                     k, v, m, (const int*)mflag, starts, qkh, qkl, out);
}